// Round 3
// baseline (1572.603 us; speedup 1.0000x reference)
//
#include <hip/hip_runtime.h>

#define N_NODES 100000
#define NUM_U 50000
#define D 64
#define NUM_E 3200000

// One wave per edge; lane = embedding dim. Coalesced 256B gather of x[src],
// 64-lane contiguous atomicAdd into agg[dst].
__global__ __launch_bounds__(256) void scatter_kernel(
    const int* __restrict__ src, const int* __restrict__ dst,
    const float* __restrict__ w, const float* __restrict__ x,
    float* __restrict__ agg, int E) {
  int lane = threadIdx.x & 63;
  int wave = (int)((blockIdx.x * blockDim.x + threadIdx.x) >> 6);
  int nwaves = (int)((gridDim.x * blockDim.x) >> 6);
  for (int e = wave; e < E; e += nwaves) {
    int s = src[e];
    int d = dst[e];
    float we = w[e];
    float v = x[(size_t)s * D + lane] * we;
    atomicAdd(&agg[(size_t)d * D + lane], v);
  }
}

// out[n][j] = sum_k ((agg[n][k]+x[n][k])*0.5) * W[j][k] + b[j]
// 64 nodes per 256-thread block. W and U staged in LDS with +1 padding.
__global__ __launch_bounds__(256) void update_linear_kernel(
    const float* __restrict__ agg, const float* __restrict__ x,
    const float* __restrict__ W, const float* __restrict__ b,
    float* __restrict__ out, int N) {
  __shared__ float Wl[64][65];
  __shared__ float U[64][65];
  int t = (int)threadIdx.x;
  int lane = t & 63;
  int row = t >> 6;

  for (int i = t; i < 64 * 64; i += 256) Wl[i >> 6][i & 63] = W[i];

  int n0 = (int)blockIdx.x * 64;
#pragma unroll
  for (int i = 0; i < 16; ++i) {
    int nl = row + 4 * i;
    int n = n0 + nl;
    if (n < N)
      U[nl][lane] = (agg[(size_t)n * D + lane] + x[(size_t)n * D + lane]) * 0.5f;
  }
  __syncthreads();

  float bj = b[lane];
#pragma unroll
  for (int i = 0; i < 16; ++i) {
    int nl = row + 4 * i;
    int n = n0 + nl;
    if (n >= N) continue;
    float sum = bj;
#pragma unroll
    for (int k = 0; k < 64; ++k) sum += U[nl][k] * Wl[lane][k];
    out[(size_t)n * D + lane] = sum;
  }
}

extern "C" void kernel_launch(void* const* d_in, const int* in_sizes, int n_in,
                              void* d_out, int out_size, void* d_ws, size_t ws_size,
                              hipStream_t stream) {
  const int* edge_index = (const int*)d_in[0];
  const int* src = edge_index;            // row 0
  const int* dst = edge_index + NUM_E;    // row 1
  const float* w = (const float*)d_in[1];
  const float* user_emb = (const float*)d_in[2];
  const float* item_emb = (const float*)d_in[3];
  const float* W1 = (const float*)d_in[4];
  const float* b1 = (const float*)d_in[5];
  const float* W2 = (const float*)d_in[6];
  const float* b2 = (const float*)d_in[7];
  float* out = (float*)d_out;

  float* xA = (float*)d_ws;
  float* xB = xA + (size_t)N_NODES * D;
  float* agg = xB + (size_t)N_NODES * D;

  const size_t embBytes = (size_t)NUM_U * D * sizeof(float);
  const size_t nodeBytes = (size_t)N_NODES * D * sizeof(float);

  // x0 = concat(user_emb, item_emb)
  hipMemcpyAsync(xA, user_emb, embBytes, hipMemcpyDeviceToDevice, stream);
  hipMemcpyAsync(xA + (size_t)NUM_U * D, item_emb, embBytes,
                 hipMemcpyDeviceToDevice, stream);

  const int scatterBlocks = 4096;
  const int linBlocks = (N_NODES + 63) / 64;

  // ---- layer 1 ----
  hipMemsetAsync(agg, 0, nodeBytes, stream);
  scatter_kernel<<<scatterBlocks, 256, 0, stream>>>(src, dst, w, xA, agg, NUM_E);
  update_linear_kernel<<<linBlocks, 256, 0, stream>>>(agg, xA, W1, b1, xB, N_NODES);

  // ---- layer 2 ----
  hipMemsetAsync(agg, 0, nodeBytes, stream);
  scatter_kernel<<<scatterBlocks, 256, 0, stream>>>(src, dst, w, xB, agg, NUM_E);
  update_linear_kernel<<<linBlocks, 256, 0, stream>>>(agg, xB, W2, b2, out, N_NODES);
}

// Round 4
// 1341.329 us; speedup vs baseline: 1.1724x; 1.1724x over previous
//
#include <hip/hip_runtime.h>

#define N_NODES 100000
#define NUM_U 50000
#define D 64
#define NUM_E 3200000

// ---------- CSR build (per launch; edge list identical for both layers) ----------

__global__ __launch_bounds__(256) void hist_kernel(
    const int* __restrict__ dst, int* __restrict__ cnt) {
  int i = blockIdx.x * blockDim.x + threadIdx.x;
  int stride = gridDim.x * blockDim.x;
  for (int e = i; e < NUM_E; e += stride) atomicAdd(&cnt[dst[e]], 1);
}

// Single-block exclusive scan of cnt[0..N) -> rowptr[0..N], rowptr[N]=E.
__global__ __launch_bounds__(1024) void scan_kernel(
    const int* __restrict__ cnt, int* __restrict__ rowptr) {
  __shared__ int ps[1024];
  int t = (int)threadIdx.x;
  const int CH = (N_NODES + 1023) / 1024;  // 98
  int lo = t * CH;
  int hi = min(lo + CH, N_NODES);
  int s = 0;
  for (int i = lo; i < hi; ++i) s += cnt[i];
  ps[t] = s;
  __syncthreads();
  for (int off = 1; off < 1024; off <<= 1) {
    int add = (t >= off) ? ps[t - off] : 0;
    __syncthreads();
    ps[t] += add;
    __syncthreads();
  }
  int run = ps[t] - s;  // exclusive base for this chunk
  for (int i = lo; i < hi; ++i) {
    rowptr[i] = run;
    run += cnt[i];
  }
  if (t == 0) rowptr[N_NODES] = NUM_E;
}

// Permute src/w into dst-sorted order. Order within a node is nondeterministic
// (int atomics) -> only fp-sum reordering, same as the atomic baseline.
__global__ __launch_bounds__(256) void fill_kernel(
    const int* __restrict__ src, const int* __restrict__ dst,
    const float* __restrict__ w, const int* __restrict__ rowptr,
    int* __restrict__ cursor, int* __restrict__ srcp, float* __restrict__ wp) {
  int i = blockIdx.x * blockDim.x + threadIdx.x;
  int stride = gridDim.x * blockDim.x;
  for (int e = i; e < NUM_E; e += stride) {
    int d = dst[e];
    int pos = rowptr[d] + atomicAdd(&cursor[d], 1);
    srcp[pos] = src[e];
    wp[pos] = w[e];
  }
}

// ---------- Fused gather + residual + linear ----------
// One wave per destination node; lane = embedding dim.
// out[n][j] = b[j] + sum_k u[k]*W[j][k],  u = (sum_e x[src_e]*w_e + x[n]) * 0.5
// Source rows selected from (xu, xi) so layer 1 reads the raw emb inputs
// (no concat copy) and layer 2 passes xu=xB, xi=xB+NUM_U*D (same code path).
__global__ __launch_bounds__(256) void fused_gcn_kernel(
    const int* __restrict__ rowptr, const int* __restrict__ srcp,
    const float* __restrict__ wp, const float* __restrict__ xu,
    const float* __restrict__ xi, const float* __restrict__ W,
    const float* __restrict__ b, float* __restrict__ out) {
  __shared__ float Wl[64][65];
  int t = (int)threadIdx.x;
  for (int i = t; i < 64 * 64; i += 256) Wl[i >> 6][i & 63] = W[i];
  __syncthreads();

  int lane = t & 63;
  int wid = (int)((blockIdx.x * blockDim.x + t) >> 6);
  int nw = (int)((gridDim.x * blockDim.x) >> 6);
  float bj = b[lane];

  for (int n = wid; n < N_NODES; n += nw) {
    int lo = rowptr[n], hi = rowptr[n + 1];
    float acc = 0.f;
    for (int j0 = lo; j0 < hi; j0 += 64) {
      int j = j0 + lane;
      int s = 0;
      float wv = 0.f;
      if (j < hi) {
        s = srcp[j];
        wv = wp[j];
      }
      int cnt = min(hi - j0, 64);
      for (int k = 0; k < cnt; ++k) {
        int sk = __shfl(s, k);
        float wk = __shfl(wv, k);
        const float* xr =
            (sk < NUM_U) ? (xu + (size_t)sk * D) : (xi + (size_t)(sk - NUM_U) * D);
        acc = fmaf(xr[lane], wk, acc);
      }
    }
    const float* xn =
        (n < NUM_U) ? (xu + (size_t)n * D) : (xi + (size_t)(n - NUM_U) * D);
    float u = (acc + xn[lane]) * 0.5f;

    float sum = bj;
#pragma unroll
    for (int k = 0; k < 64; ++k) {
      float uk = __shfl(u, k);
      sum = fmaf(uk, Wl[lane][k], sum);
    }
    out[(size_t)n * D + lane] = sum;
  }
}

extern "C" void kernel_launch(void* const* d_in, const int* in_sizes, int n_in,
                              void* d_out, int out_size, void* d_ws, size_t ws_size,
                              hipStream_t stream) {
  const int* edge_index = (const int*)d_in[0];
  const int* src = edge_index;          // row 0
  const int* dst = edge_index + NUM_E;  // row 1
  const float* w = (const float*)d_in[1];
  const float* user_emb = (const float*)d_in[2];
  const float* item_emb = (const float*)d_in[3];
  const float* W1 = (const float*)d_in[4];
  const float* b1 = (const float*)d_in[5];
  const float* W2 = (const float*)d_in[6];
  const float* b2 = (const float*)d_in[7];
  float* out = (float*)d_out;

  // workspace layout (~52.4 MB)
  float* xB = (float*)d_ws;                          // N*D floats
  int* srcp = (int*)(xB + (size_t)N_NODES * D);      // E ints
  float* wp = (float*)(srcp + NUM_E);                // E floats
  int* rowptr = (int*)(wp + NUM_E);                  // N+1 ints
  int* cnt = rowptr + (N_NODES + 1);                 // N ints
  int* cursor = cnt + N_NODES;                       // N ints

  // zero cnt + cursor (adjacent)
  hipMemsetAsync(cnt, 0, (size_t)2 * N_NODES * sizeof(int), stream);

  // CSR build (amortized over both layers)
  hist_kernel<<<2048, 256, 0, stream>>>(dst, cnt);
  scan_kernel<<<1, 1024, 0, stream>>>(cnt, rowptr);
  fill_kernel<<<2048, 256, 0, stream>>>(src, dst, w, rowptr, cursor, srcp, wp);

  const int fusedBlocks = 2048;  // 8192 waves, grid-stride over 100K nodes

  // layer 1: reads raw user/item embeddings, writes xB
  fused_gcn_kernel<<<fusedBlocks, 256, 0, stream>>>(rowptr, srcp, wp, user_emb,
                                                    item_emb, W1, b1, xB);
  // layer 2: reads xB (xi = xB + NUM_U*D keeps the same indexing), writes out
  fused_gcn_kernel<<<fusedBlocks, 256, 0, stream>>>(
      rowptr, srcp, wp, xB, xB + (size_t)NUM_U * D, W2, b2, out);
}

// Round 5
// 739.544 us; speedup vs baseline: 2.1264x; 1.8137x over previous
//
#include <hip/hip_runtime.h>

#define N_NODES 100000
#define NUM_U 50000
#define D 64
#define NUM_E 3200000
#define NP 100352            // 98*1024, padded node count for the scan
#define SCAN_BLOCKS 98

// ---- micro: M = (W2@W1)^T (stored row k, col j), c = b1@W2^T, cc = 0.5c+b2 ----
__global__ __launch_bounds__(256) void micro_kernel(
    const float* __restrict__ W1, const float* __restrict__ W2,
    const float* __restrict__ b1, const float* __restrict__ b2,
    float* __restrict__ M, float* __restrict__ c, float* __restrict__ cc) {
  __shared__ float w1[64][65], w2[64][65];
  int t = (int)threadIdx.x;
  for (int i = t; i < 4096; i += 256) { w1[i >> 6][i & 63] = W1[i]; w2[i >> 6][i & 63] = W2[i]; }
  __syncthreads();
  for (int i = t; i < 4096; i += 256) {
    int k = i >> 6, j = i & 63;
    float s = 0.f;
#pragma unroll
    for (int tt = 0; tt < 64; ++tt) s = fmaf(w2[j][tt], w1[tt][k], s);
    M[i] = s;  // M[k][j]
  }
  if (t < 64) {
    float s = 0.f;
#pragma unroll
    for (int tt = 0; tt < 64; ++tt) s = fmaf(b1[tt], w2[t][tt], s);
    c[t] = s;
    cc[t] = 0.5f * s + b2[t];
  }
}

// ---- z = x @ M  (x = concat(user,item) via per-row pointer select) ----
__global__ __launch_bounds__(256) void zmm_kernel(
    const float* __restrict__ xu, const float* __restrict__ xi,
    const float* __restrict__ M, float* __restrict__ z) {
  __shared__ float Mt[64][65];  // Mt[j][k] = M[k][j]
  __shared__ float U[64][65];
  int t = (int)threadIdx.x;
  for (int i = t; i < 4096; i += 256) Mt[i & 63][i >> 6] = M[i];
  int lane = t & 63, row = t >> 6;
  int n0 = (int)blockIdx.x * 64;
#pragma unroll
  for (int i = 0; i < 16; ++i) {
    int nl = row + 4 * i, n = n0 + nl;
    if (n < N_NODES) {
      const float* xr = (n < NUM_U) ? (xu + (size_t)n * D) : (xi + (size_t)(n - NUM_U) * D);
      U[nl][lane] = xr[lane];
    }
  }
  __syncthreads();
#pragma unroll
  for (int i = 0; i < 16; ++i) {
    int nl = row + 4 * i, n = n0 + nl;
    if (n >= N_NODES) continue;
    float s = 0.f;
#pragma unroll
    for (int k = 0; k < 64; ++k) s = fmaf(U[nl][k], Mt[lane][k], s);
    z[(size_t)n * D + lane] = s;
  }
}

// ---- CSR build ----
__global__ __launch_bounds__(256) void hist_kernel(const int4* __restrict__ dst4,
                                                   int* __restrict__ cnt) {
  int i = blockIdx.x * blockDim.x + threadIdx.x;
  int stride = gridDim.x * blockDim.x;
  for (int e = i; e < NUM_E / 4; e += stride) {
    int4 d = dst4[e];
    atomicAdd(&cnt[d.x], 1); atomicAdd(&cnt[d.y], 1);
    atomicAdd(&cnt[d.z], 1); atomicAdd(&cnt[d.w], 1);
  }
}

__global__ __launch_bounds__(256) void scan_a(const int4* __restrict__ cnt4,
                                              int* __restrict__ bsum) {
  __shared__ int red[256];
  int t = (int)threadIdx.x;
  int4 v = cnt4[blockIdx.x * 256 + t];
  red[t] = v.x + v.y + v.z + v.w;
  __syncthreads();
  for (int off = 128; off > 0; off >>= 1) {
    if (t < off) red[t] += red[t + off];
    __syncthreads();
  }
  if (t == 0) bsum[blockIdx.x] = red[0];
}

__global__ __launch_bounds__(128) void scan_b(const int* __restrict__ bsum,
                                              int* __restrict__ bbase,
                                              int* __restrict__ rowptr) {
  __shared__ int ps[128];
  int t = (int)threadIdx.x;
  int v = (t < SCAN_BLOCKS) ? bsum[t] : 0;
  ps[t] = v;
  __syncthreads();
  for (int off = 1; off < 128; off <<= 1) {
    int a = (t >= off) ? ps[t - off] : 0;
    __syncthreads();
    ps[t] += a;
    __syncthreads();
  }
  if (t < SCAN_BLOCKS) bbase[t] = ps[t] - v;  // exclusive
  if (t == 0) rowptr[N_NODES] = NUM_E;
}

__global__ __launch_bounds__(256) void scan_c(const int4* __restrict__ cnt4,
                                              const int* __restrict__ bbase,
                                              int* __restrict__ rowptr,
                                              int* __restrict__ cursor) {
  __shared__ int ps[256];
  int t = (int)threadIdx.x;
  int4 v = cnt4[blockIdx.x * 256 + t];
  int s = v.x + v.y + v.z + v.w;
  ps[t] = s;
  __syncthreads();
  for (int off = 1; off < 256; off <<= 1) {
    int a = (t >= off) ? ps[t - off] : 0;
    __syncthreads();
    ps[t] += a;
    __syncthreads();
  }
  int base = bbase[blockIdx.x] + ps[t] - s;
  int i0 = (blockIdx.x * 256 + t) * 4;
  int r0 = base, r1 = r0 + v.x, r2 = r1 + v.y, r3 = r2 + v.z;
  if (i0 + 0 < N_NODES) { rowptr[i0 + 0] = r0; cursor[i0 + 0] = r0; }
  if (i0 + 1 < N_NODES) { rowptr[i0 + 1] = r1; cursor[i0 + 1] = r1; }
  if (i0 + 2 < N_NODES) { rowptr[i0 + 2] = r2; cursor[i0 + 2] = r2; }
  if (i0 + 3 < N_NODES) { rowptr[i0 + 3] = r3; cursor[i0 + 3] = r3; }
}

__global__ __launch_bounds__(256) void fill_kernel(
    const int4* __restrict__ src4, const int4* __restrict__ dst4,
    const float4* __restrict__ w4, int* __restrict__ cursor,
    int2* __restrict__ meta) {
  int i = blockIdx.x * blockDim.x + threadIdx.x;
  int stride = gridDim.x * blockDim.x;
  for (int e = i; e < NUM_E / 4; e += stride) {
    int4 s = src4[e];
    int4 d = dst4[e];
    float4 w = w4[e];
    int p;
    p = atomicAdd(&cursor[d.x], 1); meta[p] = make_int2(s.x, __float_as_int(w.x));
    p = atomicAdd(&cursor[d.y], 1); meta[p] = make_int2(s.y, __float_as_int(w.y));
    p = atomicAdd(&cursor[d.z], 1); meta[p] = make_int2(s.z, __float_as_int(w.z));
    p = atomicAdd(&cursor[d.w], 1); meta[p] = make_int2(s.w, __float_as_int(w.w));
  }
}

// ---- pure gather: acc[n] = sum_e w_e * gsrc[src_e]; FINAL adds epilogue ----
template <bool FINAL>
__global__ __launch_bounds__(256) void gather_kernel(
    const int* __restrict__ rowptr, const int2* __restrict__ meta,
    const float* __restrict__ gsrc, const float* __restrict__ zorig,
    const float* __restrict__ c, const float* __restrict__ cc,
    float* __restrict__ outp) {
  int t = (int)threadIdx.x, lane = t & 63;
  int wid = (int)((blockIdx.x * blockDim.x + t) >> 6);
  int nw = (int)((gridDim.x * blockDim.x) >> 6);
  float cl = FINAL ? c[lane] : 0.f;
  float ccl = FINAL ? cc[lane] : 0.f;

  for (int n = wid; n < N_NODES; n += nw) {
    int lo = rowptr[n], hi = rowptr[n + 1];
    float acc0 = 0.f, acc1 = 0.f, wsum = 0.f;
    for (int j0 = lo; j0 < hi; j0 += 64) {
      int j = j0 + lane;
      int2 m = (j < hi) ? meta[j] : make_int2(0, 0);
      int cnt = min(hi - j0, 64);
      int k = 0;
      for (; k + 4 <= cnt; k += 4) {
        int s0 = __shfl(m.x, k), s1 = __shfl(m.x, k + 1);
        int s2 = __shfl(m.x, k + 2), s3 = __shfl(m.x, k + 3);
        float w0 = __int_as_float(__shfl(m.y, k));
        float w1 = __int_as_float(__shfl(m.y, k + 1));
        float w2 = __int_as_float(__shfl(m.y, k + 2));
        float w3 = __int_as_float(__shfl(m.y, k + 3));
        float v0 = gsrc[(size_t)s0 * D + lane];
        float v1 = gsrc[(size_t)s1 * D + lane];
        float v2 = gsrc[(size_t)s2 * D + lane];
        float v3 = gsrc[(size_t)s3 * D + lane];
        acc0 = fmaf(v0, w0, acc0);
        acc1 = fmaf(v1, w1, acc1);
        acc0 = fmaf(v2, w2, acc0);
        acc1 = fmaf(v3, w3, acc1);
        if (FINAL) wsum += (w0 + w1) + (w2 + w3);
      }
      for (; k < cnt; ++k) {
        int sk = __shfl(m.x, k);
        float wk = __int_as_float(__shfl(m.y, k));
        acc0 = fmaf(gsrc[(size_t)sk * D + lane], wk, acc0);
        if (FINAL) wsum += wk;
      }
    }
    float acc = acc0 + acc1;
    if (FINAL) {
      float t1n = gsrc[(size_t)n * D + lane];   // gsrc == t1 here
      float zn = zorig[(size_t)n * D + lane];
      outp[(size_t)n * D + lane] =
          0.25f * acc + 0.5f * t1n + 0.25f * zn + 0.5f * wsum * cl + ccl;
    } else {
      outp[(size_t)n * D + lane] = acc;
    }
  }
}

extern "C" void kernel_launch(void* const* d_in, const int* in_sizes, int n_in,
                              void* d_out, int out_size, void* d_ws, size_t ws_size,
                              hipStream_t stream) {
  const int* edge_index = (const int*)d_in[0];
  const int* src = edge_index;          // row 0
  const int* dst = edge_index + NUM_E;  // row 1
  const float* w = (const float*)d_in[1];
  const float* user_emb = (const float*)d_in[2];
  const float* item_emb = (const float*)d_in[3];
  const float* W1 = (const float*)d_in[4];
  const float* b1 = (const float*)d_in[5];
  const float* W2 = (const float*)d_in[6];
  const float* b2 = (const float*)d_in[7];
  float* out = (float*)d_out;

  // workspace layout (~78.2 MB)
  float* z = (float*)d_ws;                       // N*D
  float* t1 = z + (size_t)N_NODES * D;           // N*D
  int2* meta = (int2*)(t1 + (size_t)N_NODES * D);  // E int2
  int* rowptr = (int*)(meta + NUM_E);            // NP (uses N_NODES+1)
  int* cnt = rowptr + NP;                        // NP (padded, zeroed)
  int* cursor = cnt + NP;                        // NP
  int* bsum = cursor + NP;                       // 128
  int* bbase = bsum + 128;                       // 128
  float* Mbuf = (float*)(bbase + 128);           // 4096
  float* cbuf = Mbuf + 4096;                     // 64
  float* ccbuf = cbuf + 64;                      // 64

  hipMemsetAsync(cnt, 0, (size_t)NP * sizeof(int), stream);

  micro_kernel<<<1, 256, 0, stream>>>(W1, W2, b1, b2, Mbuf, cbuf, ccbuf);
  zmm_kernel<<<(N_NODES + 63) / 64, 256, 0, stream>>>(user_emb, item_emb, Mbuf, z);

  hist_kernel<<<2048, 256, 0, stream>>>((const int4*)dst, cnt);
  scan_a<<<SCAN_BLOCKS, 256, 0, stream>>>((const int4*)cnt, bsum);
  scan_b<<<1, 128, 0, stream>>>(bsum, bbase, rowptr);
  scan_c<<<SCAN_BLOCKS, 256, 0, stream>>>((const int4*)cnt, bbase, rowptr, cursor);
  fill_kernel<<<2048, 256, 0, stream>>>((const int4*)src, (const int4*)dst,
                                        (const float4*)w, cursor, meta);

  // t1 = S @ z
  gather_kernel<false><<<2048, 256, 0, stream>>>(rowptr, meta, z, z, cbuf, ccbuf, t1);
  // out = 0.25*S@t1 + 0.5*t1 + 0.25*z + 0.5*dw*c + cc
  gather_kernel<true><<<2048, 256, 0, stream>>>(rowptr, meta, t1, z, cbuf, ccbuf, out);
}